// Round 20
// baseline (319.592 us; speedup 1.0000x reference)
//
#include <hip/hip_runtime.h>

// SiameseGNN round 20: 8-slot tail burst (kill sentinel padding VALU) +
// zeroCur dispatch replaced by hipMemsetAsync.
//
// R19 evidence: agg1 46.3us, VALU 67%. Burst loop processes ceil(maxd/16)*16
// slots; maxd=max(degA,degB)~20 -> ~45% of waves burn a full 16-slot burst
// for <=8 real edges (sentinel VALU at full price) = ~25% padding.
//   fix 1: main loop emits 16-slot bursts while remaining > 8; one
//          wave-uniform-branched 8-slot burst covers the tail. maxd 17-24
//          drops 32 -> 24 slots processed.
//   fix 2: k_zeroCur deleted -- cursors + sentinel zeroed via
//          hipMemsetAsync (graph-capturable; harness uses it itself).
// Everything else unchanged from R19.

#define TPB    256
#define CHUNK  128
#define SHIFT  7
#define KMAX   1024
#define CAP    2560
#define EPB    8192
#define CPAD   16      // cursorG stride (ints)

typedef __attribute__((ext_vector_type(8))) short short8;
typedef __attribute__((ext_vector_type(4))) float f32x4;
typedef __attribute__((ext_vector_type(2))) float float2v;

struct Ctx {
    const float* X; const int* esrc; const int* edst;
    unsigned int* temp; unsigned short* Ab; unsigned char* Hs;
    unsigned int* csr; int* row_ptr; int* degA; float* dinv; int* cursorG;
    float* P; float* P2; float* outp;
};

__device__ __forceinline__ unsigned short f2bf(float x) {
    union { float f; unsigned int i; } c; c.f = x;
    unsigned int r = c.i + 0x7FFFu + ((c.i >> 16) & 1u);   // RNE
    return (unsigned short)(r >> 16);
}
__device__ __forceinline__ unsigned char f2fp8(float x) {
    int p = __builtin_amdgcn_cvt_pk_fp8_f32(x, x, 0, false);
    return (unsigned char)(p & 0xFF);
}
__device__ __forceinline__ float2v up8lo(unsigned int w) {
    return __builtin_amdgcn_cvt_pk_f32_fp8(w, false);
}
__device__ __forceinline__ float2v up8hi(unsigned int w) {
    return __builtin_amdgcn_cvt_pk_f32_fp8(w, true);
}

__global__ void k_prepW2(const float* __restrict__ W1, const float* __restrict__ W2,
                         unsigned short* __restrict__ Wt1, unsigned short* __restrict__ Wt2) {
    const float* W = blockIdx.x ? W2 : W1;
    unsigned short* Wt = blockIdx.x ? Wt2 : Wt1;
    for (int i = threadIdx.x; i < 64 * 64; i += 256) {
        int n = i >> 6, k = i & 63;
        Wt[i] = f2bf(W[k * 64 + n]);
    }
}

// binA: LDS counting sort per block, burst segment writes. 1024 threads.
__global__ __launch_bounds__(1024) void k_binA(Ctx c0, Ctx c1, int nb0, int E, int K) {
    __shared__ int cnt[KMAX];
    __shared__ int ofs[KMAX];
    __shared__ int segBase[KMAX];
    __shared__ unsigned int sorted[EPB];
    __shared__ unsigned short bkt[EPB];
    int b = blockIdx.x; Ctx c = c0;
    if (b >= nb0) { c = c1; b -= nb0; }
    int tid = threadIdx.x;               // 0..1023 == KMAX
    cnt[tid] = 0;
    __syncthreads();
    int base = b * EPB;
    int tot = E - base; if (tot > EPB) tot = EPB;
#pragma unroll
    for (int k = 0; k < EPB / 1024; ++k) {
        int e = base + k * 1024 + tid;
        if (e < E) atomicAdd(&cnt[c.edst[e] >> SHIFT], 1);
    }
    __syncthreads();
    int v = cnt[tid];
    segBase[tid] = v;
    __syncthreads();
#pragma unroll
    for (int off = 1; off < 1024; off <<= 1) {
        int t = (tid >= off) ? segBase[tid - off] : 0;
        __syncthreads();
        segBase[tid] += t;
        __syncthreads();
    }
    ofs[tid] = segBase[tid] - v;
    __syncthreads();
    if (tid < K) {
        segBase[tid] = v ? atomicAdd(&c.cursorG[tid * CPAD], v) : 0;
    } else {
        segBase[tid] = 0;
    }
    cnt[tid] = 0;
    __syncthreads();
#pragma unroll
    for (int k = 0; k < EPB / 1024; ++k) {
        int e = base + k * 1024 + tid;
        if (e < E) {
            int d = c.edst[e];
            int bk = d >> SHIFT;
            int r = atomicAdd(&cnt[bk], 1);
            int p = ofs[bk] + r;
            sorted[p] = ((unsigned int)(d & (CHUNK - 1)) << 17) | (unsigned int)c.esrc[e];
            bkt[p] = (unsigned short)bk;
        }
    }
    __syncthreads();
    for (int p = tid; p < tot; p += 1024) {
        unsigned int vv = sorted[p];
        int bk = bkt[p];
        int pos = segBase[bk] + (p - ofs[bk]);
        if (pos < CAP) c.temp[(size_t)bk * CAP + pos] = vv;
    }
}

// Per-bucket LDS counting sort -> bucket-major csr slice (stride CAP) +
// row_ptr (beg) + deg + dinv. csr stores src<<6 (pre-shifted byte offset).
__global__ __launch_bounds__(256) void k_csrb(Ctx c0, Ctx c1, int nb0, int N) {
    __shared__ int deg[CHUNK];
    __shared__ int lofs[CHUNK];
    __shared__ int cur[CHUNK];
    int b = blockIdx.x; Ctx c = c0;
    if (b >= nb0) { c = c1; b -= nb0; }
    int tid = threadIdx.x;
    if (tid < CHUNK) deg[tid] = 0;
    __syncthreads();
    int cnt = c.cursorG[b * CPAD]; if (cnt > CAP) cnt = CAP;
    const size_t tb = (size_t)b * CAP;
    for (int i = tid; i < cnt; i += 256) atomicAdd(&deg[c.temp[tb + i] >> 17], 1);
    __syncthreads();
    if (tid < CHUNK) lofs[tid] = deg[tid];
    __syncthreads();
#pragma unroll
    for (int off = 1; off < CHUNK; off <<= 1) {
        int t = (tid < CHUNK && tid >= off) ? lofs[tid - off] : 0;
        __syncthreads();
        if (tid < CHUNK) lofs[tid] += t;
        __syncthreads();
    }
    int base = b * CAP;                  // bucket-major: no global scan
    if (tid < CHUNK) {
        int excl = lofs[tid] - deg[tid];
        lofs[tid] = excl;
        cur[tid] = 0;
        int node = b * CHUNK + tid;
        if (node < N) {
            c.row_ptr[node] = base + excl;
            c.degA[node] = deg[tid];
            c.dinv[node] = rsqrtf((float)deg[tid] + 1.0f);
        }
    }
    __syncthreads();
    for (int i = tid; i < cnt; i += 256) {
        unsigned int p = c.temp[tb + i];
        int dl = p >> 17;
        int rank = atomicAdd(&cur[dl], 1);
        c.csr[base + lofs[dl] + rank] = (p & 0x1FFFFu) << 6;   // src byte offset
    }
}

// Shared MFMA body: A-fragments provided; B from Wt; store fp8 Hs.
__device__ __forceinline__ void mfma_tail(short8 a0, short8 a1,
                                          const unsigned short* __restrict__ Wt,
                                          unsigned char* __restrict__ Hs,
                                          int row0, int r, int q, int N) {
    short8 bfrag[4][2];
#pragma unroll
    for (int ct = 0; ct < 4; ++ct)
#pragma unroll
        for (int kb = 0; kb < 2; ++kb)
            bfrag[ct][kb] = *(const short8*)(Wt + (ct * 16 + r) * 64 + q * 8 + 32 * kb);
    f32x4 acc[4];
#pragma unroll
    for (int ct = 0; ct < 4; ++ct) {
        acc[ct] = (f32x4){0.0f, 0.0f, 0.0f, 0.0f};
        acc[ct] = __builtin_amdgcn_mfma_f32_16x16x32_bf16(a0, bfrag[ct][0], acc[ct], 0, 0, 0);
        acc[ct] = __builtin_amdgcn_mfma_f32_16x16x32_bf16(a1, bfrag[ct][1], acc[ct], 0, 0, 0);
    }
#pragma unroll
    for (int reg = 0; reg < 4; ++reg) {
        int row = row0 + q * 4 + reg;
        if (row < N) {
            size_t base = (size_t)row * 64 + r;
#pragma unroll
            for (int ct = 0; ct < 4; ++ct)
                Hs[base + ct * 16] = f2fp8(acc[ct][reg]);
        }
    }
}

// GEMM1: fp32 X in, dinv folded into A-fragment conversion.
__global__ __launch_bounds__(256) void k_gemm1(Ctx c0, Ctx c1, int nb0,
                                               const unsigned short* __restrict__ Wt,
                                               int nTiles, int N) {
    int b = blockIdx.x; Ctx c = c0;
    if (b >= nb0) { c = c1; b -= nb0; }
    int wave = threadIdx.x >> 6, lane = threadIdx.x & 63;
    int tile = b * 4 + wave;
    if (tile >= nTiles) return;
    int r = lane & 15, q = lane >> 4;
    int row0 = tile * 16;
    int row = row0 + r;
    int rr = row < N ? row : N - 1;
    float d = c.dinv[rr];
    const float* xrow = c.X + (size_t)rr * 64 + q * 8;
    short8 a0, a1;
#pragma unroll
    for (int j = 0; j < 8; ++j) a0[j] = (short)f2bf(xrow[j] * d);
#pragma unroll
    for (int j = 0; j < 8; ++j) a1[j] = (short)f2bf(xrow[32 + j] * d);
    mfma_tail(a0, a1, Wt, c.Hs, row0, r, q, N);
}

// GEMM2: bf16 Ab in (already dinv-scaled by aggregate1).
__global__ __launch_bounds__(256) void k_gemm2(Ctx c0, Ctx c1, int nb0,
                                               const unsigned short* __restrict__ Wt,
                                               int nTiles, int N) {
    int b = blockIdx.x; Ctx c = c0;
    if (b >= nb0) { c = c1; b -= nb0; }
    int wave = threadIdx.x >> 6, lane = threadIdx.x & 63;
    int tile = b * 4 + wave;
    if (tile >= nTiles) return;
    int r = lane & 15, q = lane >> 4;
    int row0 = tile * 16;
    const unsigned short* xrow = c.Ab + (size_t)(row0 + r) * 64 + q * 8;
    short8 a0 = *(const short8*)(xrow);
    short8 a1 = *(const short8*)(xrow + 32);
    mfma_tail(a0, a1, Wt, c.Hs, row0, r, q, N);
}

// agg block mapping: XCD-partition swizzle when swz, else linear split.
__device__ __forceinline__ void agg_map(int bi, int nb0, int swz,
                                        const Ctx& c0, const Ctx& c1,
                                        Ctx& c, int& b) {
    if (swz) {
        int graph = (bi >> 2) & 1;
        b = ((bi >> 3) << 2) | (bi & 3);
        c = graph ? c1 : c0;
    } else {
        b = bi; c = c0;
        if (b >= nb0) { c = c1; b -= nb0; }
    }
}

// 2 nodes per wave; per half: 2 groups x 16 lanes, lane s covers fp8
// channels 4s..4s+3. csr holds src<<6; gather offset = su | (s*4).
// Main loop: 16-slot bursts while remaining > 8; wave-uniform 8-slot tail.
__device__ __forceinline__ void agg_node2(const unsigned char* __restrict__ Hs,
                                          const unsigned int* __restrict__ csr,
                                          int beg, int deg, int maxd, int lane,
                                          unsigned int sent, float2v* acc) {
    int hbase = lane & 32;
    int hl = lane & 31;
    int g = (lane >> 4) & 1;
    unsigned int s4 = (unsigned int)((lane & 15) * 4);
    for (int base = 0; base < maxd; base += 32) {
        unsigned int idx = (base + hl < deg) ? csr[beg + base + hl] : sent;
        int mW = maxd - base; if (mW > 32) mW = 32;                 // wave-uniform
        int t = 0;
        for (; t + 8 < mW; t += 16) {                               // 16-slot burst
            unsigned int h[8];
#pragma unroll
            for (int u = 0; u < 8; ++u) {
                int slot = t + 2 * u + g;                           // <= 31
                unsigned int su = (unsigned int)__shfl((int)idx, hbase + slot, 64);
                h[u] = *(const unsigned int*)(Hs + (su | s4));      // saddr + voffset
            }
#pragma unroll
            for (int u = 0; u < 8; ++u) {
                acc[0] += up8lo(h[u]); acc[1] += up8hi(h[u]);       // sentinel adds 0
            }
        }
        if (t < mW) {                                               // 8-slot tail
            unsigned int h[4];
#pragma unroll
            for (int u = 0; u < 4; ++u) {
                int slot = t + 2 * u + g;
                unsigned int su = (unsigned int)__shfl((int)idx, hbase + slot, 64);
                h[u] = *(const unsigned int*)(Hs + (su | s4));
            }
#pragma unroll
            for (int u = 0; u < 4; ++u) {
                acc[0] += up8lo(h[u]); acc[1] += up8hi(h[u]);
            }
        }
    }
    // merge the half's 2 groups (bit 4); does not cross halves
#pragma unroll
    for (int k = 0; k < 2; ++k) {
        float2v o;
        o.x = __shfl_xor(acc[k].x, 16, 64); o.y = __shfl_xor(acc[k].y, 16, 64);
        acc[k] += o;
    }
}

// layer-1: Ab[d, f] = bf16( dinv[d] * relu(b[f] + dinv[d] * agg) )
__global__ __launch_bounds__(256) void k_agg1(Ctx c0, Ctx c1, int nb0, int swz,
                                              const float* __restrict__ bias, int n) {
    Ctx c; int b;
    agg_map(blockIdx.x, nb0, swz, c0, c1, c, b);
    int wave = threadIdx.x >> 6, lane = threadIdx.x & 63;
    int h = lane >> 5;
    int node = b * 8 + wave * 2 + h;
    int nd = node < n ? node : 0;
    int beg = c.row_ptr[nd];
    int deg = (node < n) ? c.degA[nd] : 0;
    int od = __shfl_xor(deg, 32, 64);
    int maxd = deg > od ? deg : od;      // wave-uniform
    float2v acc[2] = {{0.f, 0.f}, {0.f, 0.f}};
    agg_node2(c.Hs, c.csr, beg, deg, maxd, lane, (unsigned int)n << 6, acc);
    if (((lane >> 4) & 1) == 0 && node < n) {
        int s = lane & 15;
        unsigned int hv = *(const unsigned int*)(c.Hs + (size_t)node * 64 + s * 4);
        float2v h0 = up8lo(hv), h1 = up8hi(hv);
        float4 bb = *(const float4*)(bias + s * 4);
        float d = c.dinv[node];
        float v0 = fmaxf(bb.x + d * (acc[0].x + h0.x), 0.0f) * d;
        float v1 = fmaxf(bb.y + d * (acc[0].y + h0.y), 0.0f) * d;
        float v2 = fmaxf(bb.z + d * (acc[1].x + h1.x), 0.0f) * d;
        float v3 = fmaxf(bb.w + d * (acc[1].y + h1.y), 0.0f) * d;
        ushort4 o;
        o.x = f2bf(v0); o.y = f2bf(v1); o.z = f2bf(v2); o.w = f2bf(v3);
        *(ushort4*)(c.Ab + (size_t)node * 64 + s * 4) = o;
    }
}

// layer-2: block-reduce 8 relu'd rows -> P[block, f]
__global__ __launch_bounds__(256) void k_agg2(Ctx c0, Ctx c1, int nb0, int swz,
                                              const float* __restrict__ bias, int n) {
    __shared__ float red[8 * 64];
    Ctx c; int b;
    agg_map(blockIdx.x, nb0, swz, c0, c1, c, b);
    int wave = threadIdx.x >> 6, lane = threadIdx.x & 63;
    int h = lane >> 5;
    int node = b * 8 + wave * 2 + h;
    int nd = node < n ? node : 0;
    int beg = c.row_ptr[nd];
    int deg = (node < n) ? c.degA[nd] : 0;
    int od = __shfl_xor(deg, 32, 64);
    int maxd = deg > od ? deg : od;
    float2v acc[2] = {{0.f, 0.f}, {0.f, 0.f}};
    agg_node2(c.Hs, c.csr, beg, deg, maxd, lane, (unsigned int)n << 6, acc);
    if (((lane >> 4) & 1) == 0) {
        int s = lane & 15;
        float4 v = {0.f, 0.f, 0.f, 0.f};
        if (node < n) {
            unsigned int hv = *(const unsigned int*)(c.Hs + (size_t)node * 64 + s * 4);
            float2v h0 = up8lo(hv), h1 = up8hi(hv);
            float4 bb = *(const float4*)(bias + s * 4);
            float d = c.dinv[node];
            v.x = fmaxf(bb.x + d * (acc[0].x + h0.x), 0.0f);
            v.y = fmaxf(bb.y + d * (acc[0].y + h0.y), 0.0f);
            v.z = fmaxf(bb.z + d * (acc[1].x + h1.x), 0.0f);
            v.w = fmaxf(bb.w + d * (acc[1].y + h1.y), 0.0f);
        }
        *(float4*)(&red[(wave * 2 + h) * 64 + s * 4]) = v;
    }
    __syncthreads();
    if (threadIdx.x < 64) {
        float acc8 = 0.0f;
#pragma unroll
        for (int r = 0; r < 8; ++r) acc8 += red[r * 64 + threadIdx.x];
        c.P[(size_t)b * 64 + threadIdx.x] = acc8;
    }
}

// colsum -> per-block partials in P2 (no atomics, no zero pass)
__global__ void k_colsum(Ctx c0, Ctx c1, int nb0, int rows) {
    int b = blockIdx.x; Ctx c = c0;
    if (b >= nb0) { c = c1; b -= nb0; }
    int f = threadIdx.x;  // 64
    float acc = 0.0f;
    for (int r = b; r < rows; r += nb0) acc += c.P[(size_t)r * 64 + f];
    c.P2[b * 64 + f] = acc;
}

// single-wave FC: reduce 256 partial rows, then out = fcb + (S/n) @ fcw^T
__global__ void k_fc(Ctx c0, Ctx c1, const float* __restrict__ fcw,
                     const float* __restrict__ fcb, int n) {
    Ctx c = blockIdx.x ? c1 : c0;
    __shared__ float S[64];
    int j = threadIdx.x;  // 64
    float s = 0.0f;
    for (int r = 0; r < 256; ++r) s += c.P2[r * 64 + j];
    S[j] = s;
    __syncthreads();
    float inv = 1.0f / (float)n;
    float acc = fcb[j];
#pragma unroll
    for (int k = 0; k < 64; ++k) acc += (S[k] * inv) * fcw[j * 64 + k];
    c.outp[j] = acc;
}

extern "C" void kernel_launch(void* const* d_in, const int* in_sizes, int n_in,
                              void* d_out, int out_size, void* d_ws, size_t ws_size,
                              hipStream_t stream) {
    const float* x[2]  = {(const float*)d_in[0], (const float*)d_in[1]};
    const int*   ei[2] = {(const int*)d_in[2], (const int*)d_in[3]};
    const float* W1  = (const float*)d_in[4];
    const float* b1  = (const float*)d_in[5];
    const float* W2  = (const float*)d_in[6];
    const float* b2  = (const float*)d_in[7];
    const float* fcw = (const float*)d_in[8];
    const float* fcb = (const float*)d_in[9];
    float* out = (float*)d_out;

    const int N  = in_sizes[0] / 64;
    const int E  = in_sizes[2] / 2;
    const int NF = N * 64;
    const int K  = (N + CHUNK - 1) / CHUNK;     // 782 buckets
    const int gGm = (N + 7) / 8;                // aggregate blocks (8 nodes each)
    const int nTiles = (N + 15) / 16;
    const int gMf = (nTiles + 3) / 4;
    const int gBin = (E + EPB - 1) / EPB;

    auto al = [](size_t x) { return (x + 127) & ~(size_t)127; };
    size_t tempB = (size_t)K * CAP * 4;
    size_t abB   = ((size_t)NF + 64) * 2;
    size_t szRegion = al(tempB > abB ? tempB : abB);   // Ab aliases temp
    size_t szHs  = al((size_t)NF + 64);                // fp8 + sentinel row N
    size_t szCsr = al((size_t)K * CAP * 4);            // bucket-major, stride CAP
    size_t szRp  = al((size_t)N * 4);
    size_t szDeg = al((size_t)N * 4);
    size_t szDi  = al((size_t)N * 4);
    size_t szCu  = al((size_t)K * CPAD * 4);           // padded cursors
    size_t szP   = al((size_t)gGm * 64 * 4);
    size_t szP2  = al((size_t)256 * 64 * 4);
    size_t setB  = szRegion + szHs + szCsr + szRp + szDeg + szDi + szCu + szP + szP2;
    size_t wtB   = 2 * al(64 * 64 * 2);
    bool batched = ws_size >= wtB + 2 * setB;

    char* base = (char*)d_ws;
    unsigned short* Wt1 = (unsigned short*)base;
    unsigned short* Wt2 = (unsigned short*)(base + al(64 * 64 * 2));

    auto mkctx = [&](int g, char* p) {
        Ctx c;
        c.X = x[g]; c.esrc = ei[g]; c.edst = ei[g] + E;
        c.temp = (unsigned int*)p; c.Ab = (unsigned short*)p; p += szRegion;
        c.Hs = (unsigned char*)p; p += szHs;
        c.csr = (unsigned int*)p; p += szCsr;
        c.row_ptr = (int*)p; p += szRp;
        c.degA = (int*)p; p += szDeg;
        c.dinv = (float*)p; p += szDi;
        c.cursorG = (int*)p; p += szCu;
        c.P = (float*)p; p += szP;
        c.P2 = (float*)p;
        c.outp = out + g * 64;
        return c;
    };
    char* set0 = base + wtB;
    Ctx c0 = mkctx(0, set0);
    Ctx c1 = mkctx(1, batched ? set0 + setB : set0);   // fallback: shares set0

    k_prepW2<<<2, 256, 0, stream>>>(W1, W2, Wt1, Wt2);

    auto pipe = [&](Ctx A, Ctx B, int mult) {
        int swz = (mult == 2 && (gGm & 3) == 0) ? 1 : 0;
        // zero cursors + Hs sentinel row via memset (no dispatch)
        hipMemsetAsync(A.cursorG, 0, (size_t)K * CPAD * 4, stream);
        hipMemsetAsync(A.Hs + (size_t)N * 64, 0, 64, stream);
        if (mult == 2) {
            hipMemsetAsync(B.cursorG, 0, (size_t)K * CPAD * 4, stream);
            hipMemsetAsync(B.Hs + (size_t)N * 64, 0, 64, stream);
        }
        k_binA<<<mult * gBin, 1024, 0, stream>>>(A, B, gBin, E, K);
        k_csrb<<<mult * K, 256, 0, stream>>>(A, B, K, N);
        k_gemm1<<<mult * gMf, 256, 0, stream>>>(A, B, gMf, Wt1, nTiles, N);
        k_agg1<<<mult * gGm, 256, 0, stream>>>(A, B, gGm, swz, b1, N);
        k_gemm2<<<mult * gMf, 256, 0, stream>>>(A, B, gMf, Wt2, nTiles, N);
        k_agg2<<<mult * gGm, 256, 0, stream>>>(A, B, gGm, swz, b2, N);
        k_colsum<<<mult * 256, 64, 0, stream>>>(A, B, 256, gGm);
        k_fc<<<mult, 64, 0, stream>>>(A, B, fcw, fcb, N);
    };

    if (batched) {
        pipe(c0, c1, 2);
    } else {
        pipe(c0, c0, 1);   // sequential, shared buffer set
        pipe(c1, c1, 1);
    }
}